// Round 3
// baseline (397.602 us; speedup 1.0000x reference)
//
#include <hip/hip_runtime.h>

// Problem constants (B, C=1, H, W) from the reference.
#define H_ 1024
#define W_ 1024
#define B_ 16
#define TH 16                  // output rows per block
#define STEPS (TH + 6)         // input rows streamed (halo 3 each side)
#define GX (H_ / TH)           // 64 blocks in y-dim of image
#define NB2 (GX * B_)          // 1024 blocks per z-half
#define NACC 13
// partials layout (SoA): partials[j * NB2 + bid]
//  j: 0=sum_pred, then k=3,5,7: {1,5,9}=sum_dil {2,6,10}=sum_p*dil
//                               {3,7,11}=sum_ero {4,8,12}=sum_p*ero

template<bool M>
__device__ __forceinline__ float O2(float a, float b) { return M ? fmaxf(a, b) : fminf(a, b); }
template<bool M>
__device__ __forceinline__ float O3(float a, float b, float c) {
  return M ? fmaxf(fmaxf(a, b), c) : fminf(fminf(a, b), c);   // v_max3 / v_min3
}

// Sliding-row gather stencil, one extremum type per template instantiation.
// Horizontal windows h0/h3/h5/h7 built once per input row, pushed into
// register ring queues; output row y=t-3 gathered as
//   k3 = op(h3[y], h0[y-1], h0[y+1])
//   k5 = op(h5[y], h3[y-1], h3[y+1], h0[y-2], h0[y+2])
//   k7 = op(h7[y], h5[y-1], h5[y+1], h5[y-2], h5[y+2], h0[y-3], h0[y+3])
// Geodesic (exclude-OOB) border == clamped-index border here (clamped taps
// duplicate values lying in a superset part of the window) -> exact.
template<bool M>
__device__ __forceinline__ void morph_body(const float* __restrict__ pb,
                                           const float* __restrict__ tb,
                                           float* __restrict__ partials,
                                           int tid, int y0, int bid) {
  const int x0 = tid * 4;
  // dil: acc = {sum_p, s3, i3, s5, i5, s7, i7}; ero: same minus sum_p slot use
  float acc[7];
#pragma unroll
  for (int j = 0; j < 7; j++) acc[j] = 0.f;

  float h0q[7][4], h3q[5][4], h5q[6][4], h7q[4][4];

#pragma unroll
  for (int s = 0; s < STEPS; ++s) {
    const int t    = y0 + s - 3;
    const int trow = t < 0 ? 0 : (t >= H_ ? H_ - 1 : t);
    const float* tr = tb + (size_t)trow * W_;

    // a[0..11] = columns x0-4 .. x0+7, x-clamped (exact).
    float a[12];
    const float4 cv = *reinterpret_cast<const float4*>(tr + x0);
    a[4] = cv.x; a[5] = cv.y; a[6] = cv.z; a[7] = cv.w;
    if (tid > 0) {
      const float4 lv = *reinterpret_cast<const float4*>(tr + x0 - 4);
      a[0] = lv.x; a[1] = lv.y; a[2] = lv.z; a[3] = lv.w;
    } else {
      a[0] = a[1] = a[2] = a[3] = cv.x;
    }
    if (tid < 255) {
      const float4 rv = *reinterpret_cast<const float4*>(tr + x0 + 4);
      a[8] = rv.x; a[9] = rv.y; a[10] = rv.z; a[11] = rv.w;
    } else {
      a[8] = a[9] = a[10] = a[11] = cv.w;
    }

    float Q[8];
#pragma unroll
    for (int i = 1; i <= 7; ++i) Q[i] = O3<M>(a[i], a[i + 1], a[i + 2]);
#pragma unroll
    for (int c = 0; c < 4; ++c) {
      h0q[s % 7][c] = a[c + 4];
      h3q[s % 5][c] = Q[c + 3];
      h5q[s % 6][c] = O2<M>(Q[c + 2], Q[c + 4]);
      h7q[s % 4][c] = O3<M>(Q[c + 1], Q[c + 4], a[c + 7]);
    }

    if (s >= 6) {
      const float4 pv = *reinterpret_cast<const float4*>(pb + (size_t)(y0 + s - 6) * W_ + x0);
      const float p[4] = {pv.x, pv.y, pv.z, pv.w};
#pragma unroll
      for (int c = 0; c < 4; ++c) {
        const float k3 = O3<M>(h3q[(s + 2) % 5][c], h0q[(s + 3) % 7][c], h0q[(s + 5) % 7][c]);
        float k5 = O3<M>(h5q[(s + 3) % 6][c], h3q[(s + 1) % 5][c], h3q[(s + 3) % 5][c]);
        k5 = O3<M>(k5, h0q[(s + 2) % 7][c], h0q[(s + 6) % 7][c]);
        float k7 = O3<M>(h7q[(s + 1) % 4][c], h5q[(s + 2) % 6][c], h5q[(s + 4) % 6][c]);
        k7 = O3<M>(k7, h5q[(s + 1) % 6][c], h5q[(s + 5) % 6][c]);
        k7 = O3<M>(k7, h0q[(s + 1) % 7][c], h0q[s % 7][c]);

        if (M) acc[0] += p[c];
        acc[1] += k3;  acc[2] = fmaf(p[c], k3, acc[2]);
        acc[3] += k5;  acc[4] = fmaf(p[c], k5, acc[4]);
        acc[5] += k7;  acc[6] = fmaf(p[c], k7, acc[6]);
      }
    }
  }

  // wave (64-lane) shuffle reduction, then cross-wave via LDS
#pragma unroll
  for (int j = 0; j < 7; j++) {
    float v = acc[j];
#pragma unroll
    for (int off = 32; off > 0; off >>= 1) v += __shfl_down(v, off, 64);
    acc[j] = v;
  }
  __shared__ float red[4][7];
  const int lane = tid & 63, wv = tid >> 6;
  if (lane == 0) {
#pragma unroll
    for (int j = 0; j < 7; j++) red[wv][j] = acc[j];
  }
  __syncthreads();
  if (tid == 0) {
    float tot[7];
#pragma unroll
    for (int j = 0; j < 7; j++) tot[j] = red[0][j] + red[1][j] + red[2][j] + red[3][j];
    if (M) {
      partials[0 * NB2 + bid]  = tot[0];
      partials[1 * NB2 + bid]  = tot[1];  partials[2 * NB2 + bid]  = tot[2];
      partials[5 * NB2 + bid]  = tot[3];  partials[6 * NB2 + bid]  = tot[4];
      partials[9 * NB2 + bid]  = tot[5];  partials[10 * NB2 + bid] = tot[6];
    } else {
      partials[3 * NB2 + bid]  = tot[1];  partials[4 * NB2 + bid]  = tot[2];
      partials[7 * NB2 + bid]  = tot[3];  partials[8 * NB2 + bid]  = tot[4];
      partials[11 * NB2 + bid] = tot[5];  partials[12 * NB2 + bid] = tot[6];
    }
  }
}

__global__ __launch_bounds__(256, 4) void k_partials(const float* __restrict__ pred,
                                                     const float* __restrict__ tch,
                                                     float* __restrict__ partials) {
  const int b   = blockIdx.y;
  const int y0  = blockIdx.x * TH;
  const int bid = blockIdx.y * GX + blockIdx.x;
  const float* tb = tch  + (size_t)b * (H_ * W_);
  const float* pb = pred + (size_t)b * (H_ * W_);
  if (blockIdx.z == 0) morph_body<true >(pb, tb, partials, threadIdx.x, y0, bid);
  else                 morph_body<false>(pb, tb, partials, threadIdx.x, y0, bid);
}

__global__ __launch_bounds__(256) void k_final(const float* __restrict__ partials,
                                               float* __restrict__ out) {
  const int tid = threadIdx.x;
  // 52 independent coalesced loads -> full MLP, then double accumulate.
  float v[NACC][4];
#pragma unroll
  for (int j = 0; j < NACC; j++)
#pragma unroll
    for (int k = 0; k < 4; k++)
      v[j][k] = partials[j * NB2 + tid + k * 256];

  double acc[NACC];
#pragma unroll
  for (int j = 0; j < NACC; j++)
    acc[j] = ((double)v[j][0] + v[j][1]) + ((double)v[j][2] + v[j][3]);

#pragma unroll
  for (int j = 0; j < NACC; j++) {
#pragma unroll
    for (int off = 32; off > 0; off >>= 1) acc[j] += __shfl_down(acc[j], off, 64);
  }
  __shared__ double red[4][NACC];
  const int lane = tid & 63, wv = tid >> 6;
  if (lane == 0) {
#pragma unroll
    for (int j = 0; j < NACC; j++) red[wv][j] = acc[j];
  }
  __syncthreads();
  if (tid == 0) {
    double t_[NACC];
#pragma unroll
    for (int j = 0; j < NACC; j++) t_[j] = red[0][j] + red[1][j] + red[2][j] + red[3][j];
    const double Sp = t_[0];
    double total = 0.0;
#pragma unroll
    for (int k = 0; k < 3; k++) {
      const double Sd = t_[1 + 4 * k], Id = t_[2 + 4 * k];
      const double Se = t_[3 + 4 * k], Ie = t_[4 + 4 * k];
      double cd = Sp + Sd; if (cd < 1e-7) cd = 1e-7;
      double ce = Sp + Se; if (ce < 1e-7) ce = 1e-7;
      total += (1.0 - 2.0 * Id / cd) * (Sd > 0.0 ? 1.0 : 0.0);
      total += (1.0 - 2.0 * Ie / ce) * (Se > 0.0 ? 1.0 : 0.0);
    }
    out[0] = (float)(total / 3.0);
  }
}

extern "C" void kernel_launch(void* const* d_in, const int* in_sizes, int n_in,
                              void* d_out, int out_size, void* d_ws, size_t ws_size,
                              hipStream_t stream) {
  const float* pred = (const float*)d_in[0];  // pred_student_prob
  const float* tch  = (const float*)d_in[1];  // teacher_prob
  float* partials = (float*)d_ws;             // NACC * NB2 floats; fully written each launch

  k_partials<<<dim3(GX, B_, 2), 256, 0, stream>>>(pred, tch, partials);
  k_final<<<1, 256, 0, stream>>>(partials, (float*)d_out);
}

// Round 4
// 185.626 us; speedup vs baseline: 2.1419x; 2.1419x over previous
//
#include <hip/hip_runtime.h>

// Problem constants (B, C=1, H, W) from the reference.
#define H_ 1024
#define W_ 1024
#define B_ 16
#define TH 8                   // output rows per block (STEPS=14 fully unrolls; 22 did NOT - r3 spill disaster)
#define STEPS (TH + 6)         // input rows streamed (halo 3 each side)
#define GX (H_ / TH)           // 128 blocks in y-dim of image
#define NB2 (GX * B_)          // 2048 blocks per z-half
#define NACC 13
// partials layout (SoA): partials[j * NB2 + bid]
//  j: 0=sum_pred, then k=3,5,7: {1,5,9}=sum_dil {2,6,10}=sum_p*dil
//                               {3,7,11}=sum_ero {4,8,12}=sum_p*ero

template<bool M>
__device__ __forceinline__ float O2(float a, float b) { return M ? fmaxf(a, b) : fminf(a, b); }
template<bool M>
__device__ __forceinline__ float O3(float a, float b, float c) {
  return M ? fmaxf(fmaxf(a, b), c) : fminf(fminf(a, b), c);   // v_max3 / v_min3
}

// Sliding-row gather stencil, one extremum type per template instantiation
// (z-split halves ring state so the prefetch regs fit under the 128-VGPR /
// 4-waves-per-SIMD boundary).
// Horizontal windows h0/h3/h5/h7 built once per input row, pushed into
// register ring queues (constant indices after full unroll); output row
// y = t-3 gathered as
//   k3 = op(h3[y], h0[y-1], h0[y+1])
//   k5 = op(h5[y], h3[y-1], h3[y+1], h0[y-2], h0[y+2])
//   k7 = op(h7[y], h5[y-1], h5[y+1], h5[y-2], h5[y+2], h0[y-3], h0[y+3])
// Geodesic (exclude-OOB) border == clamped-index border (clamped taps
// duplicate values lying in a superset part of the window) -> exact.
template<bool M>
__device__ __forceinline__ void morph_body(const float* __restrict__ pb,
                                           const float* __restrict__ tb,
                                           float* __restrict__ partials,
                                           int tid, int y0, int bid) {
  const int x0 = tid * 4;
  float acc[7];
#pragma unroll
  for (int j = 0; j < 7; j++) acc[j] = 0.f;

  float h0q[7][4], h3q[5][4], h5q[6][4], h7q[4][4];

  // ---- software-pipelined loads: next-step teacher row + next-emit pred row
  float4 lvn, cvn, rvn;
  float4 pvn = make_float4(0.f, 0.f, 0.f, 0.f);
  {
    const int t0 = y0 - 3;
    const int trow = t0 < 0 ? 0 : t0;
    const float* tr = tb + (size_t)trow * W_;
    cvn = *reinterpret_cast<const float4*>(tr + x0);
    if (tid > 0)   lvn = *reinterpret_cast<const float4*>(tr + x0 - 4);
    if (tid < 255) rvn = *reinterpret_cast<const float4*>(tr + x0 + 4);
  }

#pragma unroll
  for (int s = 0; s < STEPS; ++s) {
    // consume this step's (already in-flight) loads
    const float4 cv = cvn, lv = lvn, rv = rvn;
    const float4 pv = pvn;

    // issue next step's teacher loads NOW (1 full step of latency distance)
    if (s + 1 < STEPS) {
      const int t    = y0 + s + 1 - 3;
      const int trow = t < 0 ? 0 : (t >= H_ ? H_ - 1 : t);
      const float* tr = tb + (size_t)trow * W_;
      cvn = *reinterpret_cast<const float4*>(tr + x0);
      if (tid > 0)   lvn = *reinterpret_cast<const float4*>(tr + x0 - 4);
      if (tid < 255) rvn = *reinterpret_cast<const float4*>(tr + x0 + 4);
    }
    // issue next emit's pred load (emit at step s+1 uses row y0+s-5)
    if (s >= 5 && s < STEPS - 1)
      pvn = *reinterpret_cast<const float4*>(pb + (size_t)(y0 + s - 5) * W_ + x0);

    // a[0..11] = columns x0-4 .. x0+7, x-clamped at image edges (exact).
    float a[12];
    a[4] = cv.x; a[5] = cv.y; a[6] = cv.z; a[7] = cv.w;
    if (tid > 0)   { a[0] = lv.x; a[1] = lv.y; a[2] = lv.z; a[3] = lv.w; }
    else           { a[0] = a[1] = a[2] = a[3] = cv.x; }
    if (tid < 255) { a[8] = rv.x; a[9] = rv.y; a[10] = rv.z; a[11] = rv.w; }
    else           { a[8] = a[9] = a[10] = a[11] = cv.w; }

    float Q[8];
#pragma unroll
    for (int i = 1; i <= 7; ++i) Q[i] = O3<M>(a[i], a[i + 1], a[i + 2]);
#pragma unroll
    for (int c = 0; c < 4; ++c) {
      h0q[s % 7][c] = a[c + 4];
      h3q[s % 5][c] = Q[c + 3];
      h5q[s % 6][c] = O2<M>(Q[c + 2], Q[c + 4]);
      h7q[s % 4][c] = O3<M>(Q[c + 1], Q[c + 4], a[c + 7]);
    }

    if (s >= 6) {
      const float p[4] = {pv.x, pv.y, pv.z, pv.w};
#pragma unroll
      for (int c = 0; c < 4; ++c) {
        const float k3 = O3<M>(h3q[(s + 2) % 5][c], h0q[(s + 3) % 7][c], h0q[(s + 5) % 7][c]);
        float k5 = O3<M>(h5q[(s + 3) % 6][c], h3q[(s + 1) % 5][c], h3q[(s + 3) % 5][c]);
        k5 = O3<M>(k5, h0q[(s + 2) % 7][c], h0q[(s + 6) % 7][c]);
        float k7 = O3<M>(h7q[(s + 1) % 4][c], h5q[(s + 2) % 6][c], h5q[(s + 4) % 6][c]);
        k7 = O3<M>(k7, h5q[(s + 1) % 6][c], h5q[(s + 5) % 6][c]);
        k7 = O3<M>(k7, h0q[(s + 1) % 7][c], h0q[s % 7][c]);

        if (M) acc[0] += p[c];
        acc[1] += k3;  acc[2] = fmaf(p[c], k3, acc[2]);
        acc[3] += k5;  acc[4] = fmaf(p[c], k5, acc[4]);
        acc[5] += k7;  acc[6] = fmaf(p[c], k7, acc[6]);
      }
    }
  }

  // wave (64-lane) shuffle reduction, then cross-wave via LDS
#pragma unroll
  for (int j = 0; j < 7; j++) {
    float v = acc[j];
#pragma unroll
    for (int off = 32; off > 0; off >>= 1) v += __shfl_down(v, off, 64);
    acc[j] = v;
  }
  __shared__ float red[4][7];
  const int lane = tid & 63, wv = tid >> 6;
  if (lane == 0) {
#pragma unroll
    for (int j = 0; j < 7; j++) red[wv][j] = acc[j];
  }
  __syncthreads();
  if (tid == 0) {
    float tot[7];
#pragma unroll
    for (int j = 0; j < 7; j++) tot[j] = red[0][j] + red[1][j] + red[2][j] + red[3][j];
    if (M) {
      partials[0 * NB2 + bid]  = tot[0];
      partials[1 * NB2 + bid]  = tot[1];  partials[2 * NB2 + bid]  = tot[2];
      partials[5 * NB2 + bid]  = tot[3];  partials[6 * NB2 + bid]  = tot[4];
      partials[9 * NB2 + bid]  = tot[5];  partials[10 * NB2 + bid] = tot[6];
    } else {
      partials[3 * NB2 + bid]  = tot[1];  partials[4 * NB2 + bid]  = tot[2];
      partials[7 * NB2 + bid]  = tot[3];  partials[8 * NB2 + bid]  = tot[4];
      partials[11 * NB2 + bid] = tot[5];  partials[12 * NB2 + bid] = tot[6];
    }
  }
}

__global__ __launch_bounds__(256, 2) void k_partials(const float* __restrict__ pred,
                                                     const float* __restrict__ tch,
                                                     float* __restrict__ partials) {
  const int b   = blockIdx.y;
  const int y0  = blockIdx.x * TH;
  const int bid = blockIdx.y * GX + blockIdx.x;
  const float* tb = tch  + (size_t)b * (H_ * W_);
  const float* pb = pred + (size_t)b * (H_ * W_);
  if (blockIdx.z == 0) morph_body<true >(pb, tb, partials, threadIdx.x, y0, bid);
  else                 morph_body<false>(pb, tb, partials, threadIdx.x, y0, bid);
}

__global__ __launch_bounds__(256) void k_final(const float* __restrict__ partials,
                                               float* __restrict__ out) {
  const int tid = threadIdx.x;
  double acc[NACC];
#pragma unroll
  for (int j = 0; j < NACC; j++) acc[j] = 0.0;
#pragma unroll
  for (int k = 0; k < NB2 / 256; k++) {
#pragma unroll
    for (int j = 0; j < NACC; j++)
      acc[j] += (double)partials[j * NB2 + tid + k * 256];   // coalesced, independent
  }
#pragma unroll
  for (int j = 0; j < NACC; j++) {
#pragma unroll
    for (int off = 32; off > 0; off >>= 1) acc[j] += __shfl_down(acc[j], off, 64);
  }
  __shared__ double red[4][NACC];
  const int lane = tid & 63, wv = tid >> 6;
  if (lane == 0) {
#pragma unroll
    for (int j = 0; j < NACC; j++) red[wv][j] = acc[j];
  }
  __syncthreads();
  if (tid == 0) {
    double t_[NACC];
#pragma unroll
    for (int j = 0; j < NACC; j++) t_[j] = red[0][j] + red[1][j] + red[2][j] + red[3][j];
    const double Sp = t_[0];
    double total = 0.0;
#pragma unroll
    for (int k = 0; k < 3; k++) {
      const double Sd = t_[1 + 4 * k], Id = t_[2 + 4 * k];
      const double Se = t_[3 + 4 * k], Ie = t_[4 + 4 * k];
      double cd = Sp + Sd; if (cd < 1e-7) cd = 1e-7;
      double ce = Sp + Se; if (ce < 1e-7) ce = 1e-7;
      total += (1.0 - 2.0 * Id / cd) * (Sd > 0.0 ? 1.0 : 0.0);
      total += (1.0 - 2.0 * Ie / ce) * (Se > 0.0 ? 1.0 : 0.0);
    }
    out[0] = (float)(total / 3.0);
  }
}

extern "C" void kernel_launch(void* const* d_in, const int* in_sizes, int n_in,
                              void* d_out, int out_size, void* d_ws, size_t ws_size,
                              hipStream_t stream) {
  const float* pred = (const float*)d_in[0];  // pred_student_prob
  const float* tch  = (const float*)d_in[1];  // teacher_prob
  float* partials = (float*)d_ws;             // NACC * NB2 floats; fully written each launch

  k_partials<<<dim3(GX, B_, 2), 256, 0, stream>>>(pred, tch, partials);
  k_final<<<1, 256, 0, stream>>>(partials, (float*)d_out);
}